// Round 1
// baseline (447.444 us; speedup 1.0000x reference)
//
#include <hip/hip_runtime.h>

// cluster_layer: q[n,k] = (1/(1+||x_n - c_k||^2)) normalized over k  (alpha=1)
// N=1e6, D=64, K=20. Memory-bound: 256 MB read + 80 MB write -> ~53 us floor.

#define NPTS 1000000
#define DIM  64
#define KCL  20
#define BLOCK 256
#define RPT  4   // rows per thread: amortizes LDS cluster broadcasts 16 FMAs/ds_read

__global__ __launch_bounds__(BLOCK) void cluster_q_kernel(
    const float* __restrict__ x,
    const float* __restrict__ c,
    float* __restrict__ out)
{
    __shared__ float sC[KCL * DIM];   // clusters row-major [k][j]
    __shared__ float sCsq[KCL];

    // stage clusters into LDS (coalesced)
    for (int i = threadIdx.x; i < KCL * DIM; i += BLOCK)
        sC[i] = c[i];
    __syncthreads();
    if (threadIdx.x < KCL) {
        float s = 0.f;
        #pragma unroll
        for (int j = 0; j < DIM; ++j) { float v = sC[threadIdx.x * DIM + j]; s += v * v; }
        sCsq[threadIdx.x] = s;
    }
    __syncthreads();

    const int base = blockIdx.x * (BLOCK * RPT) + threadIdx.x;

    int  row[RPT];
    bool valid[RPT];
    #pragma unroll
    for (int r = 0; r < RPT; ++r) {
        int rr = base + r * BLOCK;
        valid[r] = (rr < NPTS);
        row[r] = valid[r] ? rr : (NPTS - 1);   // clamp: duplicate load is harmless
    }

    float acc[RPT][KCL];
    float xsq[RPT];
    #pragma unroll
    for (int r = 0; r < RPT; ++r) {
        xsq[r] = 0.f;
        #pragma unroll
        for (int k = 0; k < KCL; ++k) acc[r][k] = 0.f;
    }

    const float4* __restrict__ x4 = (const float4*)x;

    #pragma unroll 2
    for (int jc = 0; jc < DIM / 4; ++jc) {
        float4 xv[RPT];
        #pragma unroll
        for (int r = 0; r < RPT; ++r)
            xv[r] = x4[row[r] * (DIM / 4) + jc];

        #pragma unroll
        for (int r = 0; r < RPT; ++r)
            xsq[r] += xv[r].x * xv[r].x + xv[r].y * xv[r].y
                    + xv[r].z * xv[r].z + xv[r].w * xv[r].w;

        #pragma unroll
        for (int k = 0; k < KCL; ++k) {
            const float4 cv = *(const float4*)&sC[k * DIM + jc * 4]; // wave-uniform -> LDS broadcast
            #pragma unroll
            for (int r = 0; r < RPT; ++r)
                acc[r][k] += xv[r].x * cv.x + xv[r].y * cv.y
                           + xv[r].z * cv.z + xv[r].w * cv.w;
        }
    }

    // epilogue: dist2 -> q -> normalize -> store (5 aligned float4 per row)
    #pragma unroll
    for (int r = 0; r < RPT; ++r) {
        if (!valid[r]) continue;
        float q[KCL];
        float s = 0.f;
        #pragma unroll
        for (int k = 0; k < KCL; ++k) {
            float d2 = xsq[r] + sCsq[k] - 2.0f * acc[r][k];
            float qq = __builtin_amdgcn_rcpf(1.0f + d2);   // v_rcp_f32, ~1 ulp
            q[k] = qq;
            s += qq;
        }
        float inv = __builtin_amdgcn_rcpf(s);
        float4* o4 = (float4*)(out + (size_t)row[r] * KCL);
        #pragma unroll
        for (int k = 0; k < KCL; k += 4) {
            float4 v;
            v.x = q[k + 0] * inv;
            v.y = q[k + 1] * inv;
            v.z = q[k + 2] * inv;
            v.w = q[k + 3] * inv;
            o4[k / 4] = v;
        }
    }
}

extern "C" void kernel_launch(void* const* d_in, const int* in_sizes, int n_in,
                              void* d_out, int out_size, void* d_ws, size_t ws_size,
                              hipStream_t stream) {
    const float* x = (const float*)d_in[0];   // (N, D) fp32
    const float* c = (const float*)d_in[1];   // (K, D) fp32
    float* out = (float*)d_out;               // (N, K) fp32

    const int rows_per_block = BLOCK * RPT;               // 1024
    const int blocks = (NPTS + rows_per_block - 1) / rows_per_block; // 977
    cluster_q_kernel<<<blocks, BLOCK, 0, stream>>>(x, c, out);
}

// Round 2
// 397.321 us; speedup vs baseline: 1.1262x; 1.1262x over previous
//
#include <hip/hip_runtime.h>

// cluster_layer: q[n,k] = (1/(1+||x_n - c_k||^2)) normalized over k  (alpha=1)
// N=1e6, D=64, K=20. Memory-bound: 256 MB read + 80 MB write -> ~53 us floor.
//
// R2: one row/thread, full 256 B row in 16 contiguous dwordx4 (per-line temporal
// locality -> MSHR merge -> fetch ~256 MB, was 494 MB with strided jc loop).
// Clusters read via wave-uniform global loads (compiler -> s_load -> SGPR operand
// in v_fma, zero extra VALU). Only csq[20] in LDS.

#define NPTS 1000000
#define DIM  64
#define KCL  20
#define BLOCK 256

__global__ __launch_bounds__(BLOCK, 4) void cluster_q_kernel(
    const float* __restrict__ x,
    const float* __restrict__ c,
    float* __restrict__ out)
{
    __shared__ float sCsq[KCL];

    // per-block csq (tiny: 20 lanes x 64 reads, c is L2-hot after block 0)
    if (threadIdx.x < KCL) {
        float s = 0.f;
        #pragma unroll
        for (int j = 0; j < DIM; ++j) {
            float v = c[threadIdx.x * DIM + j];
            s += v * v;
        }
        sCsq[threadIdx.x] = s;
    }
    __syncthreads();

    const int row = blockIdx.x * BLOCK + threadIdx.x;
    if (row >= NPTS) return;

    // load entire row: 16 contiguous float4 per lane (256 B burst)
    const float4* __restrict__ x4 = (const float4*)x + (size_t)row * (DIM / 4);
    float4 xv[DIM / 4];
    #pragma unroll
    for (int m = 0; m < DIM / 4; ++m) xv[m] = x4[m];

    float xsq = 0.f;
    #pragma unroll
    for (int m = 0; m < DIM / 4; ++m)
        xsq += xv[m].x * xv[m].x + xv[m].y * xv[m].y
             + xv[m].z * xv[m].z + xv[m].w * xv[m].w;

    // dot products: c indices are compile-time constants on a uniform pointer
    // -> scalar loads; 20 independent FMA chains for ILP
    float acc[KCL];
    #pragma unroll
    for (int k = 0; k < KCL; ++k) acc[k] = 0.f;

    #pragma unroll
    for (int m = 0; m < DIM / 4; ++m) {
        #pragma unroll
        for (int k = 0; k < KCL; ++k) {
            acc[k] += xv[m].x * c[k * DIM + 4 * m + 0]
                    + xv[m].y * c[k * DIM + 4 * m + 1]
                    + xv[m].z * c[k * DIM + 4 * m + 2]
                    + xv[m].w * c[k * DIM + 4 * m + 3];
        }
    }

    // epilogue: d2 -> q -> normalize -> 5 aligned float4 stores
    float s = 0.f;
    #pragma unroll
    for (int k = 0; k < KCL; ++k) {
        float d2 = xsq + sCsq[k] - 2.0f * acc[k];
        float qq = __builtin_amdgcn_rcpf(1.0f + d2);   // v_rcp_f32, ~1 ulp
        acc[k] = qq;
        s += qq;
    }
    const float inv = __builtin_amdgcn_rcpf(s);

    float4* o4 = (float4*)(out + (size_t)row * KCL);
    #pragma unroll
    for (int k = 0; k < KCL; k += 4) {
        float4 v;
        v.x = acc[k + 0] * inv;
        v.y = acc[k + 1] * inv;
        v.z = acc[k + 2] * inv;
        v.w = acc[k + 3] * inv;
        o4[k / 4] = v;
    }
}

extern "C" void kernel_launch(void* const* d_in, const int* in_sizes, int n_in,
                              void* d_out, int out_size, void* d_ws, size_t ws_size,
                              hipStream_t stream) {
    const float* x = (const float*)d_in[0];   // (N, D) fp32
    const float* c = (const float*)d_in[1];   // (K, D) fp32
    float* out = (float*)d_out;               // (N, K) fp32

    const int blocks = (NPTS + BLOCK - 1) / BLOCK;   // 3907
    cluster_q_kernel<<<blocks, BLOCK, 0, stream>>>(x, c, out);
}